// Round 6
// baseline (243.070 us; speedup 1.0000x reference)
//
#include <hip/hip_runtime.h>
#include <hip/hip_bf16.h>

// Problem constants
#define LNUM 8
#define ENUM 8
#define DDIM 256
#define BSZ  16384
#define H1N  64
#define H2N  32

#define BT   32     // rows per block  (grid 512 -> 2 independent blocks/CU)
#define NTHR 256    // 4 waves

// LDS pitches (u16 elements); odd 16B-granule strides -> conflict-light
#define PX   264    // x tile (D + 8)
#define PH1  72     // h1T tile (H1 + 8)   [row][feat]
#define PH2  40     // h2T tile (H2 + 8)   [row][feat]
#define PSW  9      // softmax weights pitch (floats)

// ws element offsets (u16 elems) for fragment-ordered weights
#define WS1_OFF 0           // 64 steps * 16384 elems
#define WS2_OFF 1048576     // 64 steps * 2048
#define WS3_OFF 1179648     // 64 steps * 8192

typedef float f32x4 __attribute__((ext_vector_type(4)));
typedef unsigned short u16x8 __attribute__((ext_vector_type(8)));
typedef unsigned short u16x4 __attribute__((ext_vector_type(4)));
typedef __bf16 bf16x8 __attribute__((ext_vector_type(8)));

#define Z4 ((f32x4){0.f, 0.f, 0.f, 0.f})

// f32 -> bf16 RTNE via native cast (compiler pairs into v_cvt_pk_bf16_f32).
static __device__ __forceinline__ unsigned short f2bf(float f) {
    __bf16 h = (__bf16)f;
    return __builtin_bit_cast(unsigned short, h);
}

// D[m][n] = sum_k A[m][k]*B[n][k] + C : A supplies m, B supplies n, frags are
// symmetric [idx16][K] -> swapping args transposes the output tile.
static __device__ __forceinline__ f32x4 mfma16(u16x8 a, u16x8 b, f32x4 c) {
    return __builtin_amdgcn_mfma_f32_16x16x32_bf16(
        __builtin_bit_cast(bf16x8, a), __builtin_bit_cast(bf16x8, b), c, 0, 0, 0);
}

// Barrier with lgkmcnt-only drain: LDS producer/consumer ordering preserved,
// in-flight GLOBAL loads are NOT drained (vs __syncthreads' vmcnt(0)).
// Safe: all inter-wave data flows through LDS; no global stores in the loop.
// HW-validated rounds 2/4/5.
static __device__ __forceinline__ void lbar() {
    asm volatile("s_waitcnt lgkmcnt(0)" ::: "memory");
    __builtin_amdgcn_s_barrier();
    asm volatile("" ::: "memory");
}

// ---------------------------------------------------------------------------
// Kernel 1: fp32 weights -> bf16 B-fragment layout. Unchanged.
// Fragment: 64 lanes x 8 elems; slot (q*16+r) holds W[n0+r][k0+q*8 .. +7].
// ---------------------------------------------------------------------------
__global__ __launch_bounds__(256) void cvt_w_frag(
    const float* __restrict__ w1, const float* __restrict__ w2,
    const float* __restrict__ w3, unsigned short* __restrict__ ws)
{
    int gid = blockIdx.x * 256 + threadIdx.x;
    const float* src;
    unsigned short* dst;
    if (gid < 131072) {                          // W1: [s][n(64)][k(256)]
        int s = gid >> 11, rem = gid & 2047;
        int n = rem >> 5, kc = rem & 31;
        int nt = n >> 4, r = n & 15, kt = kc >> 2, q = kc & 3;
        src = w1 + (size_t)gid * 8;
        dst = ws + WS1_OFF + (size_t)s * 16384 + nt * 4096 + kt * 512 + (q * 16 + r) * 8;
    } else if (gid < 147456) {                   // W2: [s][n(32)][k(64)]
        int g = gid - 131072;
        int s = g >> 8, rem = g & 255;
        int n = rem >> 3, kc = rem & 7;
        int n2 = n >> 4, r = n & 15, kt = kc >> 2, q = kc & 3;
        src = w2 + (size_t)g * 8;
        dst = ws + WS2_OFF + (size_t)s * 2048 + n2 * 1024 + kt * 512 + (q * 16 + r) * 8;
    } else {                                     // W3: [s][n(256)][k(32)]
        int g = gid - 147456;
        int s = g >> 10, rem = g & 1023;
        int n = rem >> 2, q = rem & 3;
        int nt = n >> 4, r = n & 15;
        src = w3 + (size_t)g * 8;
        dst = ws + WS3_OFF + (size_t)s * 8192 + nt * 512 + (q * 16 + r) * 8;
    }
    float4 a = *(const float4*)src;
    float4 b = *(const float4*)(src + 4);
    u16x8 p;
    p[0] = f2bf(a.x); p[1] = f2bf(a.y); p[2] = f2bf(a.z); p[3] = f2bf(a.w);
    p[4] = f2bf(b.x); p[5] = f2bf(b.y); p[6] = f2bf(b.z); p[7] = f2bf(b.w);
    *(u16x8*)dst = p;
}

// ---------------------------------------------------------------------------
// Kernel 2: fused 8-layer x 8-expert MoE MLP.
// Skewed single-barrier pipeline: per layer (P = expert-pair index 0..3,
// parity p = P&1, H1T/H2T double-buffered by parity):
//   fill : G1(P0)->H1T[0]                                   | bar
//   k=0  : G2(P0)  + G1(P1)->H1T[1]                         | bar
//   k=1,2: G2(Pk) + G3(Pk-1) + G1(Pk+1)   (52 MFMA/phase)   | bar
//   k=3  : G2(P3) + G3(P2)                                  | bar
//   drain: G3(P3); layer transition
// One barrier per phase (54 total vs 78). Every weight load is issued and
// consumed within one barrier-free phase (W1 covered by G2+G3 ~500cyc) ->
// NO registers live across barriers (rounds 2/5 failure mode eliminated).
// __launch_bounds__(256,4) pins VGPR<=128: 2-block/CU residency guaranteed.
// ---------------------------------------------------------------------------
__global__ __launch_bounds__(NTHR, 4) void moe_fused(
    const float* __restrict__ src, const unsigned short* __restrict__ Wf,
    const float* __restrict__ b1, const float* __restrict__ b2,
    const float* __restrict__ b3, const float* __restrict__ masks,
    float* __restrict__ out)
{
    __shared__ __align__(16) unsigned short Xlds[BT * PX];          // 16896 B
    __shared__ __align__(16) unsigned short H1T[2][2][BT * PH1];    // 18432 B [par][e][row*feat]
    __shared__ __align__(16) unsigned short H2T[2][2][BT * PH2];    // 10240 B [par][e][row*feat]
    __shared__ float SWlds[BT * PSW];                               //  1152 B
    // total 46720 B -> 2 blocks/CU (93440 <= 160K)

    const int tid  = threadIdx.x;
    const int lane = tid & 63;
    const int wn   = tid >> 6;      // {0..3}: feat grp (G1), col grp (G3)
    const int rg   = wn & 1;        // G2 row group
    const int fg   = wn >> 1;       // G2 feat group
    const int n15  = lane & 15;
    const int q    = lane >> 4;
    const int b0   = blockIdx.x * BT;

    const unsigned short* w1base = Wf + WS1_OFF + wn * 4096 + lane * 8;  // feat grp wn
    const unsigned short* w2base = Wf + WS2_OFF + fg * 1024 + lane * 8;  // feat grp fg
    const unsigned short* w3base = Wf + WS3_OFF + wn * 2048 + lane * 8;  // out grp wn

    u16x8 xf[2][8];          // persistent x B-frags: rows mt*16, K=256
    f32x4 ACC[2][4];         // output accumulator (C-layout: row=q*4+rr, col=n15)

    auto stage_softmax = [&](int l) {
        if (tid < BT) {
            const float* mp = masks + ((size_t)l * BSZ + b0 + tid) * ENUM;
            float4 m0 = *(const float4*)mp;
            float4 m1 = *(const float4*)(mp + 4);
            float mv[8] = {m0.x, m0.y, m0.z, m0.w, m1.x, m1.y, m1.z, m1.w};
            float mx = mv[0];
            #pragma unroll
            for (int e = 1; e < 8; ++e) mx = fmaxf(mx, mv[e]);
            float s = 0.f;
            #pragma unroll
            for (int e = 0; e < 8; ++e) { mv[e] = expf(mv[e] - mx); s += mv[e]; }
            float inv = 1.f / s;
            #pragma unroll
            for (int e = 0; e < 8; ++e) SWlds[tid * PSW + e] = mv[e] * inv;
        }
    };

    // ACC = sum_e softmax_w[row][e] * b3[e][col]  (fp32 VALU, once per layer)
    auto acc_init = [&](int l) {
        const float* b3l = b3 + (size_t)l * ENUM * DDIM;
        #pragma unroll
        for (int mt = 0; mt < 2; ++mt)
            #pragma unroll
            for (int nt = 0; nt < 4; ++nt) ACC[mt][nt] = Z4;
        #pragma unroll 2
        for (int e2 = 0; e2 < ENUM; ++e2) {
            float swv[2][4];
            #pragma unroll
            for (int mt = 0; mt < 2; ++mt)
                #pragma unroll
                for (int rr = 0; rr < 4; ++rr)
                    swv[mt][rr] = SWlds[(mt*16 + q*4 + rr) * PSW + e2];
            #pragma unroll
            for (int nt = 0; nt < 4; ++nt) {
                float bv = b3l[e2 * DDIM + wn*64 + nt*16 + n15];
                #pragma unroll
                for (int mt = 0; mt < 2; ++mt)
                    #pragma unroll
                    for (int rr = 0; rr < 4; ++rr)
                        ACC[mt][nt][rr] += swv[mt][rr] * bv;
            }
        }
    };

    auto xf_read = [&]() {
        #pragma unroll
        for (int mt = 0; mt < 2; ++mt)
            #pragma unroll
            for (int kt = 0; kt < 8; ++kt)
                xf[mt][kt] = *(const u16x8*)
                    &Xlds[(mt*16 + n15) * PX + q*8 + kt*32];
    };
    auto x_write = [&]() {
        #pragma unroll
        for (int mt = 0; mt < 2; ++mt)
            #pragma unroll
            for (int nt = 0; nt < 4; ++nt)
                #pragma unroll
                for (int rr = 0; rr < 4; ++rr)
                    Xlds[(mt*16 + q*4 + rr) * PX + wn*64 + nt*16 + n15] =
                        f2bf(ACC[mt][nt][rr]);
    };

    // ---------------- weight/bias load helpers (P = expert-pair idx) -------
    auto load_W1p = [&](int P, u16x8* A, u16x8* B) {
        const unsigned short* pA = w1base + (size_t)(2*P) * 16384;
        const unsigned short* pB = pA + 16384;
        #pragma unroll
        for (int kt = 0; kt < 8; ++kt) {
            A[kt] = *(const u16x8*)(pA + kt * 512);
            B[kt] = *(const u16x8*)(pB + kt * 512);
        }
    };
    auto load_W2p = [&](int P, u16x8* A, u16x8* B) {
        const unsigned short* qA = w2base + (size_t)(2*P) * 2048;
        const unsigned short* qB = qA + 2048;
        A[0] = *(const u16x8*)(qA);  A[1] = *(const u16x8*)(qA + 512);
        B[0] = *(const u16x8*)(qB);  B[1] = *(const u16x8*)(qB + 512);
    };
    auto load_W3p = [&](int P, u16x8* A, u16x8* B) {
        const unsigned short* pA = w3base + (size_t)(2*P) * 8192;
        const unsigned short* pB = pA + 8192;
        #pragma unroll
        for (int nt = 0; nt < 4; ++nt) {
            A[nt] = *(const u16x8*)(pA + nt * 512);
            B[nt] = *(const u16x8*)(pB + nt * 512);
        }
    };

    // ---------------- pipeline stages -------------------------------------
    // G1(P): h1 = relu(W1 x + b1), transposed -> H1T[par][e][row][feat]
    auto do_G1 = [&](int par, const u16x8* wfA, const u16x8* wfB,
                     float4 bb1A, float4 bb1B) {
        f32x4 a1A[2] = {Z4, Z4}, a1B[2] = {Z4, Z4};
        __builtin_amdgcn_s_setprio(1);
        #pragma unroll
        for (int kt = 0; kt < 8; ++kt) {
            a1A[0] = mfma16(wfA[kt], xf[0][kt], a1A[0]);
            a1A[1] = mfma16(wfA[kt], xf[1][kt], a1A[1]);
            a1B[0] = mfma16(wfB[kt], xf[0][kt], a1B[0]);
            a1B[1] = mfma16(wfB[kt], xf[1][kt], a1B[1]);
        }
        __builtin_amdgcn_s_setprio(0);
        #pragma unroll
        for (int mt = 0; mt < 2; ++mt) {
            u16x4 pkA, pkB;
            #pragma unroll
            for (int rr = 0; rr < 4; ++rr) {
                pkA[rr] = f2bf(fmaxf(a1A[mt][rr] + bb1A[rr], 0.f));
                pkB[rr] = f2bf(fmaxf(a1B[mt][rr] + bb1B[rr], 0.f));
            }
            int row = mt*16 + n15;
            *(u16x4*)&H1T[par][0][row * PH1 + wn*16 + q*4] = pkA;
            *(u16x4*)&H1T[par][1][row * PH1 + wn*16 + q*4] = pkB;
        }
    };

    // G2(P): h2 = relu(W2 h1 + b2) * sw[e], transposed -> H2T[par][e]
    auto do_G2 = [&](int e0, int par, const u16x8* w2A, const u16x8* w2B,
                     float4 bb2A, float4 bb2B) {
        f32x4 a2A = Z4, a2B = Z4;
        int hrow = rg*16 + n15;
        u16x8 hA0 = *(const u16x8*)&H1T[par][0][hrow * PH1 + q*8];
        u16x8 hA1 = *(const u16x8*)&H1T[par][0][hrow * PH1 + q*8 + 32];
        u16x8 hB0 = *(const u16x8*)&H1T[par][1][hrow * PH1 + q*8];
        u16x8 hB1 = *(const u16x8*)&H1T[par][1][hrow * PH1 + q*8 + 32];
        a2A = mfma16(w2A[0], hA0, a2A);
        a2B = mfma16(w2B[0], hB0, a2B);
        a2A = mfma16(w2A[1], hA1, a2A);
        a2B = mfma16(w2B[1], hB1, a2B);
        float swA = SWlds[hrow * PSW + e0];
        float swB = SWlds[hrow * PSW + e0 + 1];
        u16x4 pkA, pkB;
        #pragma unroll
        for (int rr = 0; rr < 4; ++rr) {
            pkA[rr] = f2bf(fmaxf(a2A[rr] + bb2A[rr], 0.f) * swA);
            pkB[rr] = f2bf(fmaxf(a2B[rr] + bb2B[rr], 0.f) * swB);
        }
        *(u16x4*)&H2T[par][0][hrow * PH2 + fg*16 + q*4] = pkA;
        *(u16x4*)&H2T[par][1][hrow * PH2 + fg*16 + q*4] = pkB;
    };

    // G3(P): ACC += h2 @ W3^T (8 independent chains)
    auto do_G3 = [&](int par, const u16x8* w3A, const u16x8* w3B) {
        u16x8 hA0 = *(const u16x8*)&H2T[par][0][(n15) * PH2 + q*8];
        u16x8 hA1 = *(const u16x8*)&H2T[par][0][(16 + n15) * PH2 + q*8];
        u16x8 hB0 = *(const u16x8*)&H2T[par][1][(n15) * PH2 + q*8];
        u16x8 hB1 = *(const u16x8*)&H2T[par][1][(16 + n15) * PH2 + q*8];
        __builtin_amdgcn_s_setprio(1);
        #pragma unroll
        for (int nt = 0; nt < 4; ++nt) {
            ACC[0][nt] = mfma16(hA0, w3A[nt], ACC[0][nt]);
            ACC[1][nt] = mfma16(hA1, w3A[nt], ACC[1][nt]);
        }
        #pragma unroll
        for (int nt = 0; nt < 4; ++nt) {
            ACC[0][nt] = mfma16(hB0, w3B[nt], ACC[0][nt]);
            ACC[1][nt] = mfma16(hB1, w3B[nt], ACC[1][nt]);
        }
        __builtin_amdgcn_s_setprio(0);
    };

    auto ld_bb1 = [&](int P, float4& A, float4& B) {
        A = *(const float4*)(b1 + (2*P) * 64 + wn * 16 + q * 4);
        B = *(const float4*)(b1 + (2*P + 1) * 64 + wn * 16 + q * 4);
    };
    auto ld_bb2 = [&](int P, float4& A, float4& B) {
        A = *(const float4*)(b2 + (2*P) * 32 + fg * 16 + q * 4);
        B = *(const float4*)(b2 + (2*P + 1) * 32 + fg * 16 + q * 4);
    };

    // ================= prologue =================
    #pragma unroll
    for (int i = 0; i < 4; ++i) {                // stage layer-0 x (bf16)
        int o = (i * NTHR + tid) * 8;
        int r = o >> 8, c = o & 255;
        const float* p = src + (size_t)(b0 + r) * DDIM + c;
        float4 f0 = *(const float4*)(p);
        float4 f1 = *(const float4*)(p + 4);
        u16x8 pk;
        pk[0] = f2bf(f0.x); pk[1] = f2bf(f0.y); pk[2] = f2bf(f0.z); pk[3] = f2bf(f0.w);
        pk[4] = f2bf(f1.x); pk[5] = f2bf(f1.y); pk[6] = f2bf(f1.z); pk[7] = f2bf(f1.w);
        *(u16x8*)&Xlds[r * PX + c] = pk;
    }
    stage_softmax(0);
    __syncthreads();
    xf_read();
    acc_init(0);

    // ================= layer loop (skewed pipeline inside) =================
    #pragma unroll 1
    for (int l = 0; l < LNUM; ++l) {
        const int P0 = 4 * l;

        // ---- fill: G1(P0) -> H1T[0] ----
        {
            u16x8 wfA[8], wfB[8]; float4 bb1A, bb1B;
            load_W1p(P0, wfA, wfB); ld_bb1(P0, bb1A, bb1B);
            do_G1(0, wfA, wfB, bb1A, bb1B);
            lbar();
        }
        // ---- k=0: G2(P0) + G1(P1)->H1T[1] ----
        {
            u16x8 w2A[2], w2B[2], wfA[8], wfB[8];
            float4 bb2A, bb2B, bb1A, bb1B;
            load_W2p(P0, w2A, w2B); load_W1p(P0 + 1, wfA, wfB);
            ld_bb2(P0, bb2A, bb2B); ld_bb1(P0 + 1, bb1A, bb1B);
            do_G2(0, 0, w2A, w2B, bb2A, bb2B);
            do_G1(1, wfA, wfB, bb1A, bb1B);
            lbar();
        }
        // ---- k=1: G2(P1) + G3(P0) + G1(P2)->H1T[0] ----
        {
            u16x8 w2A[2], w2B[2], w3A[4], w3B[4], wfA[8], wfB[8];
            float4 bb2A, bb2B, bb1A, bb1B;
            load_W2p(P0 + 1, w2A, w2B); load_W3p(P0, w3A, w3B);
            load_W1p(P0 + 2, wfA, wfB);
            ld_bb2(P0 + 1, bb2A, bb2B); ld_bb1(P0 + 2, bb1A, bb1B);
            do_G2(2, 1, w2A, w2B, bb2A, bb2B);
            do_G3(0, w3A, w3B);
            do_G1(0, wfA, wfB, bb1A, bb1B);
            lbar();
        }
        // ---- k=2: G2(P2) + G3(P1) + G1(P3)->H1T[1] ----
        {
            u16x8 w2A[2], w2B[2], w3A[4], w3B[4], wfA[8], wfB[8];
            float4 bb2A, bb2B, bb1A, bb1B;
            load_W2p(P0 + 2, w2A, w2B); load_W3p(P0 + 1, w3A, w3B);
            load_W1p(P0 + 3, wfA, wfB);
            ld_bb2(P0 + 2, bb2A, bb2B); ld_bb1(P0 + 3, bb1A, bb1B);
            do_G2(4, 0, w2A, w2B, bb2A, bb2B);
            do_G3(1, w3A, w3B);
            do_G1(1, wfA, wfB, bb1A, bb1B);
            lbar();
        }
        // ---- k=3: G2(P3) + G3(P2) ----
        {
            u16x8 w2A[2], w2B[2], w3A[4], w3B[4];
            float4 bb2A, bb2B;
            load_W2p(P0 + 3, w2A, w2B); load_W3p(P0 + 2, w3A, w3B);
            ld_bb2(P0 + 3, bb2A, bb2B);
            do_G2(6, 1, w2A, w2B, bb2A, bb2B);
            do_G3(0, w3A, w3B);
            lbar();
        }
        // ---- drain: G3(P3) ----
        {
            u16x8 w3A[4], w3B[4];
            load_W3p(P0 + 3, w3A, w3B);
            do_G3(1, w3A, w3B);
        }

        // ---- layer transition ----
        if (l < LNUM - 1) {
            x_write();
            lbar();
            xf_read();
            stage_softmax(l + 1);
            lbar();
            acc_init(l + 1);
        }
    }

    // ================= final store (fp32) =================
    #pragma unroll
    for (int mt = 0; mt < 2; ++mt)
        #pragma unroll
        for (int nt = 0; nt < 4; ++nt)
            #pragma unroll
            for (int rr = 0; rr < 4; ++rr)
                out[(size_t)(b0 + mt*16 + q*4 + rr) * DDIM
                    + wn*64 + nt*16 + n15] = ACC[mt][nt][rr];
}

extern "C" void kernel_launch(void* const* d_in, const int* in_sizes, int n_in,
                              void* d_out, int out_size, void* d_ws, size_t ws_size,
                              hipStream_t stream) {
    const float* src   = (const float*)d_in[0];
    const float* W1    = (const float*)d_in[1];
    const float* b1    = (const float*)d_in[2];
    const float* W2    = (const float*)d_in[3];
    const float* b2    = (const float*)d_in[4];
    const float* W3    = (const float*)d_in[5];
    const float* b3    = (const float*)d_in[6];
    const float* masks = (const float*)d_in[7];
    float* out = (float*)d_out;
    unsigned short* ws = (unsigned short*)d_ws;   // needs 3,407,872 B

    hipLaunchKernelGGL(cvt_w_frag, dim3(832), dim3(256), 0, stream, W1, W2, W3, ws);
    hipLaunchKernelGGL(moe_fused, dim3(BSZ / BT), dim3(NTHR), 0, stream,
                       src, ws, b1, b2, b3, masks, out);
}

// Round 7
// 182.340 us; speedup vs baseline: 1.3331x; 1.3331x over previous
//
#include <hip/hip_runtime.h>
#include <hip/hip_bf16.h>

// Problem constants
#define LNUM 8
#define ENUM 8
#define DDIM 256
#define BSZ  16384
#define H1N  64
#define H2N  32

#define BT   32     // rows per block  (grid 512 -> 2 independent blocks/CU)
#define NTHR 256    // 4 waves

// LDS pitches (u16 elements); odd 16B-granule strides -> conflict-light
#define PX   264    // x tile (D + 8)
#define PH1  72     // h1T tile (H1 + 8)   [row][feat]
#define PH2  40     // h2T tile (H2 + 8)   [row][feat]
#define PSW  9      // softmax weights pitch (floats)

// ws element offsets (u16 elems) for fragment-ordered weights
#define WS1_OFF 0           // 64 steps * 16384 elems
#define WS2_OFF 1048576     // 64 steps * 2048
#define WS3_OFF 1179648     // 64 steps * 8192

typedef float f32x4 __attribute__((ext_vector_type(4)));
typedef unsigned short u16x8 __attribute__((ext_vector_type(8)));
typedef unsigned short u16x4 __attribute__((ext_vector_type(4)));
typedef __bf16 bf16x8 __attribute__((ext_vector_type(8)));

#define Z4 ((f32x4){0.f, 0.f, 0.f, 0.f})

// f32 -> bf16 RTNE via native cast (compiler pairs into v_cvt_pk_bf16_f32).
static __device__ __forceinline__ unsigned short f2bf(float f) {
    __bf16 h = (__bf16)f;
    return __builtin_bit_cast(unsigned short, h);
}

// D[m][n] = sum_k A[m][k]*B[n][k] + C : A supplies m, B supplies n, frags are
// symmetric [idx16][K] -> swapping args transposes the output tile.
static __device__ __forceinline__ f32x4 mfma16(u16x8 a, u16x8 b, f32x4 c) {
    return __builtin_amdgcn_mfma_f32_16x16x32_bf16(
        __builtin_bit_cast(bf16x8, a), __builtin_bit_cast(bf16x8, b), c, 0, 0, 0);
}

// Barrier with lgkmcnt-only drain: LDS producer/consumer ordering preserved,
// in-flight GLOBAL loads are NOT drained (vs __syncthreads' vmcnt(0)).
// Safe: all inter-wave data flows through LDS; no global stores in the loop.
// HW-validated rounds 2/4/5/6.
static __device__ __forceinline__ void lbar() {
    asm volatile("s_waitcnt lgkmcnt(0)" ::: "memory");
    __builtin_amdgcn_s_barrier();
    asm volatile("" ::: "memory");
}

// ---------------------------------------------------------------------------
// Kernel 1: fp32 weights -> bf16 B-fragment layout. Unchanged.
// Fragment: 64 lanes x 8 elems; slot (q*16+r) holds W[n0+r][k0+q*8 .. +7].
// ---------------------------------------------------------------------------
__global__ __launch_bounds__(256) void cvt_w_frag(
    const float* __restrict__ w1, const float* __restrict__ w2,
    const float* __restrict__ w3, unsigned short* __restrict__ ws)
{
    int gid = blockIdx.x * 256 + threadIdx.x;
    const float* src;
    unsigned short* dst;
    if (gid < 131072) {                          // W1: [s][n(64)][k(256)]
        int s = gid >> 11, rem = gid & 2047;
        int n = rem >> 5, kc = rem & 31;
        int nt = n >> 4, r = n & 15, kt = kc >> 2, q = kc & 3;
        src = w1 + (size_t)gid * 8;
        dst = ws + WS1_OFF + (size_t)s * 16384 + nt * 4096 + kt * 512 + (q * 16 + r) * 8;
    } else if (gid < 147456) {                   // W2: [s][n(32)][k(64)]
        int g = gid - 131072;
        int s = g >> 8, rem = g & 255;
        int n = rem >> 3, kc = rem & 7;
        int n2 = n >> 4, r = n & 15, kt = kc >> 2, q = kc & 3;
        src = w2 + (size_t)g * 8;
        dst = ws + WS2_OFF + (size_t)s * 2048 + n2 * 1024 + kt * 512 + (q * 16 + r) * 8;
    } else {                                     // W3: [s][n(256)][k(32)]
        int g = gid - 147456;
        int s = g >> 10, rem = g & 1023;
        int n = rem >> 2, q = rem & 3;
        int nt = n >> 4, r = n & 15;
        src = w3 + (size_t)g * 8;
        dst = ws + WS3_OFF + (size_t)s * 8192 + nt * 512 + (q * 16 + r) * 8;
    }
    float4 a = *(const float4*)src;
    float4 b = *(const float4*)(src + 4);
    u16x8 p;
    p[0] = f2bf(a.x); p[1] = f2bf(a.y); p[2] = f2bf(a.z); p[3] = f2bf(a.w);
    p[4] = f2bf(b.x); p[5] = f2bf(b.y); p[6] = f2bf(b.z); p[7] = f2bf(b.w);
    *(u16x8*)dst = p;
}

// ---------------------------------------------------------------------------
// Kernel 2: fused 8-layer x 8-expert MoE MLP, 2-expert supersteps.
// R4 structure (BT=32, 4 waves, 2 blocks/CU, lgkmcnt-only barriers) with G3
// SKEWED one superstep: iteration ss issues W1/W2(ss), then runs G3(ss-1)
// (16 independent MFMAs) to cover their L2 latency, then G1(ss). G3 of the
// layer's last pair drains at P==3 before the layer transition. Phase
// contents and register liveness are IDENTICAL to R4 (w3A/w3B loop-carried,
// 16 regs across 2 barriers) -> VGPR stays ~96, 2 blocks/CU preserved.
// ---------------------------------------------------------------------------
__global__ __launch_bounds__(NTHR, 2) void moe_fused(
    const float* __restrict__ src, const unsigned short* __restrict__ Wf,
    const float* __restrict__ b1, const float* __restrict__ b2,
    const float* __restrict__ b3, const float* __restrict__ masks,
    float* __restrict__ out)
{
    __shared__ __align__(16) unsigned short Xlds[BT * PX];        // 16896 B
    __shared__ __align__(16) unsigned short H1T[2][BT * PH1];     //  9216 B [e][row*feat]
    __shared__ __align__(16) unsigned short H2T[2][BT * PH2];     //  5120 B [e][row*feat]
    __shared__ float SWlds[BT * PSW];                             //  1152 B
    // total 32384 B -> 2 blocks/CU

    const int tid  = threadIdx.x;
    const int lane = tid & 63;
    const int wn   = tid >> 6;      // {0..3}: feat grp (G1), col grp (G3)
    const int rg   = wn & 1;        // G2 row group
    const int fg   = wn >> 1;       // G2 feat group
    const int n15  = lane & 15;
    const int q    = lane >> 4;
    const int b0   = blockIdx.x * BT;

    const unsigned short* w1base = Wf + WS1_OFF + wn * 4096 + lane * 8;  // feat grp wn
    const unsigned short* w2base = Wf + WS2_OFF + fg * 1024 + lane * 8;  // feat grp fg
    const unsigned short* w3base = Wf + WS3_OFF + wn * 2048 + lane * 8;  // out grp wn

    u16x8 xf[2][8];          // persistent x B-frags: rows mt*16, K=256
    f32x4 ACC[2][4];         // output accumulator (C-layout: row=q*4+rr, col=n15)
    u16x8 w3A[4], w3B[4];    // loop-carried W3 frags (consumed by skewed G3)

    auto stage_softmax = [&](int l) {
        if (tid < BT) {
            const float* mp = masks + ((size_t)l * BSZ + b0 + tid) * ENUM;
            float4 m0 = *(const float4*)mp;
            float4 m1 = *(const float4*)(mp + 4);
            float mv[8] = {m0.x, m0.y, m0.z, m0.w, m1.x, m1.y, m1.z, m1.w};
            float mx = mv[0];
            #pragma unroll
            for (int e = 1; e < 8; ++e) mx = fmaxf(mx, mv[e]);
            float s = 0.f;
            #pragma unroll
            for (int e = 0; e < 8; ++e) { mv[e] = expf(mv[e] - mx); s += mv[e]; }
            float inv = 1.f / s;
            #pragma unroll
            for (int e = 0; e < 8; ++e) SWlds[tid * PSW + e] = mv[e] * inv;
        }
    };

    // ACC = sum_e softmax_w[row][e] * b3[e][col]  (fp32 VALU, once per layer)
    auto acc_init = [&](int l) {
        const float* b3l = b3 + (size_t)l * ENUM * DDIM;
        #pragma unroll
        for (int mt = 0; mt < 2; ++mt)
            #pragma unroll
            for (int nt = 0; nt < 4; ++nt) ACC[mt][nt] = Z4;
        #pragma unroll 2
        for (int e2 = 0; e2 < ENUM; ++e2) {
            float swv[2][4];
            #pragma unroll
            for (int mt = 0; mt < 2; ++mt)
                #pragma unroll
                for (int rr = 0; rr < 4; ++rr)
                    swv[mt][rr] = SWlds[(mt*16 + q*4 + rr) * PSW + e2];
            #pragma unroll
            for (int nt = 0; nt < 4; ++nt) {
                float bv = b3l[e2 * DDIM + wn*64 + nt*16 + n15];
                #pragma unroll
                for (int mt = 0; mt < 2; ++mt)
                    #pragma unroll
                    for (int rr = 0; rr < 4; ++rr)
                        ACC[mt][nt][rr] += swv[mt][rr] * bv;
            }
        }
    };

    auto xf_read = [&]() {
        #pragma unroll
        for (int mt = 0; mt < 2; ++mt)
            #pragma unroll
            for (int kt = 0; kt < 8; ++kt)
                xf[mt][kt] = *(const u16x8*)
                    &Xlds[(mt*16 + n15) * PX + q*8 + kt*32];
    };
    auto x_write = [&]() {
        #pragma unroll
        for (int mt = 0; mt < 2; ++mt)
            #pragma unroll
            for (int nt = 0; nt < 4; ++nt)
                #pragma unroll
                for (int rr = 0; rr < 4; ++rr)
                    Xlds[(mt*16 + q*4 + rr) * PX + wn*64 + nt*16 + n15] =
                        f2bf(ACC[mt][nt][rr]);
    };

    // G3: ACC += h2 @ W3^T (8 independent chains), consumes w3A/w3B + H2T.
    auto do_G3 = [&]() {
        u16x8 hA0 = *(const u16x8*)&H2T[0][(n15) * PH2 + q*8];
        u16x8 hA1 = *(const u16x8*)&H2T[0][(16 + n15) * PH2 + q*8];
        u16x8 hB0 = *(const u16x8*)&H2T[1][(n15) * PH2 + q*8];
        u16x8 hB1 = *(const u16x8*)&H2T[1][(16 + n15) * PH2 + q*8];
        #pragma unroll
        for (int nt = 0; nt < 4; ++nt) {
            ACC[0][nt] = mfma16(hA0, w3A[nt], ACC[0][nt]);
            ACC[1][nt] = mfma16(hA1, w3A[nt], ACC[1][nt]);
        }
        #pragma unroll
        for (int nt = 0; nt < 4; ++nt) {
            ACC[0][nt] = mfma16(hB0, w3B[nt], ACC[0][nt]);
            ACC[1][nt] = mfma16(hB1, w3B[nt], ACC[1][nt]);
        }
    };

    // ================= prologue =================
    #pragma unroll
    for (int i = 0; i < 4; ++i) {                // stage layer-0 x (bf16)
        int o = (i * NTHR + tid) * 8;
        int r = o >> 8, c = o & 255;
        const float* p = src + (size_t)(b0 + r) * DDIM + c;
        float4 f0 = *(const float4*)(p);
        float4 f1 = *(const float4*)(p + 4);
        u16x8 pk;
        pk[0] = f2bf(f0.x); pk[1] = f2bf(f0.y); pk[2] = f2bf(f0.z); pk[3] = f2bf(f0.w);
        pk[4] = f2bf(f1.x); pk[5] = f2bf(f1.y); pk[6] = f2bf(f1.z); pk[7] = f2bf(f1.w);
        *(u16x8*)&Xlds[r * PX + c] = pk;
    }
    stage_softmax(0);
    __syncthreads();
    xf_read();
    acc_init(0);

    // ================= superstep loop: 2 experts per iteration =================
    // P = ss & 3 (expert-pair index within layer). G3 skewed: iteration ss
    // runs G3(ss-1) after issuing this superstep's W1/W2 loads; the layer's
    // last G3 drains at P==3 (before the transition, so ACC is complete).
    #pragma unroll 1
    for (int ss = 0; ss < LNUM * ENUM / 2; ++ss) {
        const int s0 = 2 * ss, s1 = s0 + 1;
        const int l  = s0 >> 3, e0 = s0 & 7, e1 = s1 & 7;
        const int P  = ss & 3;

        // ---- issue W1/W2 loads + biases FIRST (G3 below covers them) ----
        u16x8 wfA[8], wfB[8], w2A[2], w2B[2];
        {
            const unsigned short* pA = w1base + (size_t)s0 * 16384;
            const unsigned short* pB = w1base + (size_t)s1 * 16384;
            #pragma unroll
            for (int kt = 0; kt < 8; ++kt) {
                wfA[kt] = *(const u16x8*)(pA + kt * 512);
                wfB[kt] = *(const u16x8*)(pB + kt * 512);
            }
            const unsigned short* q2A = w2base + (size_t)s0 * 2048;
            const unsigned short* q2B = w2base + (size_t)s1 * 2048;
            w2A[0] = *(const u16x8*)(q2A);  w2A[1] = *(const u16x8*)(q2A + 512);
            w2B[0] = *(const u16x8*)(q2B);  w2B[1] = *(const u16x8*)(q2B + 512);
        }
        const float4 bb1A = *(const float4*)(b1 + s0 * 64 + wn * 16 + q * 4);
        const float4 bb1B = *(const float4*)(b1 + s1 * 64 + wn * 16 + q * 4);
        const float4 bb2A = *(const float4*)(b2 + s0 * 32 + fg * 16 + q * 4);
        const float4 bb2B = *(const float4*)(b2 + s1 * 32 + fg * 16 + q * 4);

        // ---- skewed G3(ss-1): 16 independent MFMAs cover the W1/W2 L2
        //      round trip. H2T written before B2(ss-1), read here (after) ----
        if (P > 0) do_G3();

        // ---- G1 both experts (transposed): lane -> feats wn*16+q*4+rr ----
        f32x4 a1A[2] = {Z4, Z4}, a1B[2] = {Z4, Z4};
        #pragma unroll
        for (int kt = 0; kt < 8; ++kt) {
            a1A[0] = mfma16(wfA[kt], xf[0][kt], a1A[0]);
            a1A[1] = mfma16(wfA[kt], xf[1][kt], a1A[1]);
            a1B[0] = mfma16(wfB[kt], xf[0][kt], a1B[0]);
            a1B[1] = mfma16(wfB[kt], xf[1][kt], a1B[1]);
        }

        // ---- W3(ss) loads (wf regs dead): consumed by G3 at next iter top
        //      (or the P==3 drain). In flight across B1+G2+B2: full cover ----
        {
            const unsigned short* p3A = w3base + (size_t)s0 * 8192;
            const unsigned short* p3B = w3base + (size_t)s1 * 8192;
            #pragma unroll
            for (int nt = 0; nt < 4; ++nt) {
                w3A[nt] = *(const u16x8*)(p3A + nt * 512);
                w3B[nt] = *(const u16x8*)(p3B + nt * 512);
            }
        }

        // ---- G1 epilogues: relu+bias, pack 4 feats -> one b64 per (mt,expert) ----
        #pragma unroll
        for (int mt = 0; mt < 2; ++mt) {
            u16x4 pkA, pkB;
            #pragma unroll
            for (int rr = 0; rr < 4; ++rr) {
                pkA[rr] = f2bf(fmaxf(a1A[mt][rr] + bb1A[rr], 0.f));
                pkB[rr] = f2bf(fmaxf(a1B[mt][rr] + bb1B[rr], 0.f));
            }
            int row = mt*16 + n15;
            *(u16x4*)&H1T[0][row * PH1 + wn*16 + q*4] = pkA;
            *(u16x4*)&H1T[1][row * PH1 + wn*16 + q*4] = pkB;
        }
        lbar();                             // B1: h1 ready; W3 stays in flight

        // ---- G2 both experts (transposed): lane -> h2 feats fg*16+q*4+rr,
        //      rows rg*16+n15 ----
        f32x4 a2A = Z4, a2B = Z4;
        {
            int hrow = rg*16 + n15;
            u16x8 hA0 = *(const u16x8*)&H1T[0][hrow * PH1 + q*8];
            u16x8 hA1 = *(const u16x8*)&H1T[0][hrow * PH1 + q*8 + 32];
            u16x8 hB0 = *(const u16x8*)&H1T[1][hrow * PH1 + q*8];
            u16x8 hB1 = *(const u16x8*)&H1T[1][hrow * PH1 + q*8 + 32];
            a2A = mfma16(w2A[0], hA0, a2A);
            a2B = mfma16(w2B[0], hB0, a2B);
            a2A = mfma16(w2A[1], hA1, a2A);
            a2B = mfma16(w2B[1], hB1, a2B);
        }
        {
            int row = rg*16 + n15;
            float swA = SWlds[row * PSW + e0];
            float swB = SWlds[row * PSW + e1];
            u16x4 pkA, pkB;
            #pragma unroll
            for (int rr = 0; rr < 4; ++rr) {
                pkA[rr] = f2bf(fmaxf(a2A[rr] + bb2A[rr], 0.f) * swA);
                pkB[rr] = f2bf(fmaxf(a2B[rr] + bb2B[rr], 0.f) * swB);
            }
            *(u16x4*)&H2T[0][row * PH2 + fg*16 + q*4] = pkA;
            *(u16x4*)&H2T[1][row * PH2 + fg*16 + q*4] = pkB;
        }
        lbar();                             // B2: h2 ready

        // ---- layer end: drain G3(P3), then transition (ACC now complete) ----
        if (P == 3) {
            do_G3();
            if (l < LNUM - 1) {
                x_write();
                lbar();
                xf_read();
                stage_softmax(l + 1);
                lbar();
                acc_init(l + 1);
            }
        }
    }

    // ================= final store (fp32) =================
    #pragma unroll
    for (int mt = 0; mt < 2; ++mt)
        #pragma unroll
        for (int nt = 0; nt < 4; ++nt)
            #pragma unroll
            for (int rr = 0; rr < 4; ++rr)
                out[(size_t)(b0 + mt*16 + q*4 + rr) * DDIM
                    + wn*64 + nt*16 + n15] = ACC[mt][nt][rr];
}

extern "C" void kernel_launch(void* const* d_in, const int* in_sizes, int n_in,
                              void* d_out, int out_size, void* d_ws, size_t ws_size,
                              hipStream_t stream) {
    const float* src   = (const float*)d_in[0];
    const float* W1    = (const float*)d_in[1];
    const float* b1    = (const float*)d_in[2];
    const float* W2    = (const float*)d_in[3];
    const float* b2    = (const float*)d_in[4];
    const float* W3    = (const float*)d_in[5];
    const float* b3    = (const float*)d_in[6];
    const float* masks = (const float*)d_in[7];
    float* out = (float*)d_out;
    unsigned short* ws = (unsigned short*)d_ws;   // needs 3,407,872 B

    hipLaunchKernelGGL(cvt_w_frag, dim3(832), dim3(256), 0, stream, W1, W2, W3, ws);
    hipLaunchKernelGGL(moe_fused, dim3(BSZ / BT), dim3(NTHR), 0, stream,
                       src, ws, b1, b2, b3, masks, out);
}

// Round 8
// 175.479 us; speedup vs baseline: 1.3852x; 1.0391x over previous
//
#include <hip/hip_runtime.h>
#include <hip/hip_bf16.h>

// Problem constants
#define LNUM 8
#define ENUM 8
#define DDIM 256
#define BSZ  16384
#define H1N  64
#define H2N  32

#define BT   32     // rows per block  (grid 512 -> 2 blocks/CU)
#define NTHR 256    // 4 waves

// LDS pitches (u16 elements); odd 16B-granule strides -> conflict-light
#define PX   264    // x tile (D + 8)
#define PH1  72     // h1 tile pitch (H1 + 8)   [row][feat]
#define PH2  40     // h2 tile pitch (H2 + 8)   [row][feat]
#define PSW  9      // softmax weights pitch (floats)

// ws element offsets (u16 elems) for fragment-ordered weights
#define WS1_OFF 0           // 64 steps * 16384 elems
#define WS2_OFF 1048576     // 64 steps * 2048
#define WS3_OFF 1179648     // 64 steps * 8192

typedef float f32x4 __attribute__((ext_vector_type(4)));
typedef unsigned short u16x8 __attribute__((ext_vector_type(8)));
typedef unsigned short u16x4 __attribute__((ext_vector_type(4)));
typedef __bf16 bf16x8 __attribute__((ext_vector_type(8)));

#define Z4 ((f32x4){0.f, 0.f, 0.f, 0.f})

// f32 -> bf16 RTNE via native cast (compiler pairs into v_cvt_pk_bf16_f32).
static __device__ __forceinline__ unsigned short f2bf(float f) {
    __bf16 h = (__bf16)f;
    return __builtin_bit_cast(unsigned short, h);
}

// D[m][n] = sum_k A[m][k]*B[n][k] + C : A supplies m, B supplies n, frags are
// symmetric [idx16][K] -> swapping args transposes the output tile.
static __device__ __forceinline__ f32x4 mfma16(u16x8 a, u16x8 b, f32x4 c) {
    return __builtin_amdgcn_mfma_f32_16x16x32_bf16(
        __builtin_bit_cast(bf16x8, a), __builtin_bit_cast(bf16x8, b), c, 0, 0, 0);
}

// Barrier with lgkmcnt-only drain: LDS producer/consumer ordering preserved,
// in-flight GLOBAL loads are NOT drained (vs __syncthreads' vmcnt(0)).
// Safe: all inter-wave data flows through LDS; no global stores in the loop.
// HW-validated rounds 2/4/5/6/7.
static __device__ __forceinline__ void lbar() {
    asm volatile("s_waitcnt lgkmcnt(0)" ::: "memory");
    __builtin_amdgcn_s_barrier();
    asm volatile("" ::: "memory");
}

// ---------------------------------------------------------------------------
// Kernel 1: fp32 weights -> bf16 B-fragment layout. Unchanged.
// Fragment: 64 lanes x 8 elems; slot (q*16+r) holds W[n0+r][k0+q*8 .. +7].
// ---------------------------------------------------------------------------
__global__ __launch_bounds__(256) void cvt_w_frag(
    const float* __restrict__ w1, const float* __restrict__ w2,
    const float* __restrict__ w3, unsigned short* __restrict__ ws)
{
    int gid = blockIdx.x * 256 + threadIdx.x;
    const float* src;
    unsigned short* dst;
    if (gid < 131072) {                          // W1: [s][n(64)][k(256)]
        int s = gid >> 11, rem = gid & 2047;
        int n = rem >> 5, kc = rem & 31;
        int nt = n >> 4, r = n & 15, kt = kc >> 2, q = kc & 3;
        src = w1 + (size_t)gid * 8;
        dst = ws + WS1_OFF + (size_t)s * 16384 + nt * 4096 + kt * 512 + (q * 16 + r) * 8;
    } else if (gid < 147456) {                   // W2: [s][n(32)][k(64)]
        int g = gid - 131072;
        int s = g >> 8, rem = g & 255;
        int n = rem >> 3, kc = rem & 7;
        int n2 = n >> 4, r = n & 15, kt = kc >> 2, q = kc & 3;
        src = w2 + (size_t)g * 8;
        dst = ws + WS2_OFF + (size_t)s * 2048 + n2 * 1024 + kt * 512 + (q * 16 + r) * 8;
    } else {                                     // W3: [s][n(256)][k(32)]
        int g = gid - 147456;
        int s = g >> 10, rem = g & 1023;
        int n = rem >> 2, q = rem & 3;
        int nt = n >> 4, r = n & 15;
        src = w3 + (size_t)g * 8;
        dst = ws + WS3_OFF + (size_t)s * 8192 + nt * 512 + (q * 16 + r) * 8;
    }
    float4 a = *(const float4*)src;
    float4 b = *(const float4*)(src + 4);
    u16x8 p;
    p[0] = f2bf(a.x); p[1] = f2bf(a.y); p[2] = f2bf(a.z); p[3] = f2bf(a.w);
    p[4] = f2bf(b.x); p[5] = f2bf(b.y); p[6] = f2bf(b.z); p[7] = f2bf(b.w);
    *(u16x8*)dst = p;
}

// ---------------------------------------------------------------------------
// Kernel 2: fused 8-layer x 8-expert MoE MLP — expert-per-wave pipeline.
// Wave w owns experts {w, w+4}: G1 (x@W1^T, 4 feat-tiles) and G2 (h1@W2^T)
// run end-to-end per expert with the h1 transpose through a WAVE-PRIVATE
// LDS region (intra-wave lgkmcnt ordering, NO barrier). h2 goes to a
// per-expert shared region; ONE barrier, then every wave runs G3 over all
// 8 experts for its column group. 3 barriers/layer (vs 8-10 in R4), all
// weight loads sit in barrier-free straight-line code where wave-slip
// (8 waves/CU, unsynced) hides L2 latency. acc_init deferred to post-barrier
// so ACC is dead during G1/G2 and xf is dead during G3 -> no weight state
// live across any barrier (the R2/R5/R6/R7 failure mode).
// ---------------------------------------------------------------------------
__global__ __launch_bounds__(NTHR, 2) void moe_fused(
    const float* __restrict__ src, const unsigned short* __restrict__ Wf,
    const float* __restrict__ b1, const float* __restrict__ b2,
    const float* __restrict__ b3, const float* __restrict__ masks,
    float* __restrict__ out)
{
    __shared__ __align__(16) unsigned short Xlds[BT * PX];        // 16896 B
    __shared__ __align__(16) unsigned short H1W[4][BT * PH1];     // 18432 B wave-private
    __shared__ __align__(16) unsigned short H2T[8][BT * PH2];     // 20480 B per-expert
    __shared__ float SWlds[BT * PSW];                             //  1152 B
    // total 56960 B -> 2 blocks/CU (113920 <= 160K)

    const int tid  = threadIdx.x;
    const int lane = tid & 63;
    const int wv   = tid >> 6;      // wave id: expert base (G1/G2), col grp (G3)
    const int n15  = lane & 15;
    const int q    = lane >> 4;
    const int b0   = blockIdx.x * BT;

    const unsigned short* w3base = Wf + WS3_OFF + wv * 2048 + lane * 8;

    u16x8 xf[2][8];          // persistent x B-frags (dead during G3)
    f32x4 ACC[2][4];         // output accumulator (dead during G1/G2)

    auto stage_softmax = [&](int l) {
        if (tid < BT) {
            const float* mp = masks + ((size_t)l * BSZ + b0 + tid) * ENUM;
            float4 m0 = *(const float4*)mp;
            float4 m1 = *(const float4*)(mp + 4);
            float mv[8] = {m0.x, m0.y, m0.z, m0.w, m1.x, m1.y, m1.z, m1.w};
            float mx = mv[0];
            #pragma unroll
            for (int e = 1; e < 8; ++e) mx = fmaxf(mx, mv[e]);
            float s = 0.f;
            #pragma unroll
            for (int e = 0; e < 8; ++e) { mv[e] = expf(mv[e] - mx); s += mv[e]; }
            float inv = 1.f / s;
            #pragma unroll
            for (int e = 0; e < 8; ++e) SWlds[tid * PSW + e] = mv[e] * inv;
        }
    };

    // ACC = sum_e softmax_w[row][e] * b3[e][col]  (fp32 VALU, once per layer)
    auto acc_init = [&](int l) {
        const float* b3l = b3 + (size_t)l * ENUM * DDIM;
        #pragma unroll
        for (int mt = 0; mt < 2; ++mt)
            #pragma unroll
            for (int nt = 0; nt < 4; ++nt) ACC[mt][nt] = Z4;
        #pragma unroll 2
        for (int e2 = 0; e2 < ENUM; ++e2) {
            float swv[2][4];
            #pragma unroll
            for (int mt = 0; mt < 2; ++mt)
                #pragma unroll
                for (int rr = 0; rr < 4; ++rr)
                    swv[mt][rr] = SWlds[(mt*16 + q*4 + rr) * PSW + e2];
            #pragma unroll
            for (int nt = 0; nt < 4; ++nt) {
                float bv = b3l[e2 * DDIM + wv*64 + nt*16 + n15];
                #pragma unroll
                for (int mt = 0; mt < 2; ++mt)
                    #pragma unroll
                    for (int rr = 0; rr < 4; ++rr)
                        ACC[mt][nt][rr] += swv[mt][rr] * bv;
            }
        }
    };

    auto xf_read = [&]() {
        #pragma unroll
        for (int mt = 0; mt < 2; ++mt)
            #pragma unroll
            for (int kt = 0; kt < 8; ++kt)
                xf[mt][kt] = *(const u16x8*)
                    &Xlds[(mt*16 + n15) * PX + q*8 + kt*32];
    };
    auto x_write = [&]() {
        #pragma unroll
        for (int mt = 0; mt < 2; ++mt)
            #pragma unroll
            for (int nt = 0; nt < 4; ++nt)
                #pragma unroll
                for (int rr = 0; rr < 4; ++rr)
                    Xlds[(mt*16 + q*4 + rr) * PX + wv*64 + nt*16 + n15] =
                        f2bf(ACC[mt][nt][rr]);
    };

    // ================= prologue =================
    #pragma unroll
    for (int i = 0; i < 4; ++i) {                // stage layer-0 x (bf16)
        int o = (i * NTHR + tid) * 8;
        int r = o >> 8, c = o & 255;
        const float* p = src + (size_t)(b0 + r) * DDIM + c;
        float4 f0 = *(const float4*)(p);
        float4 f1 = *(const float4*)(p + 4);
        u16x8 pk;
        pk[0] = f2bf(f0.x); pk[1] = f2bf(f0.y); pk[2] = f2bf(f0.z); pk[3] = f2bf(f0.w);
        pk[4] = f2bf(f1.x); pk[5] = f2bf(f1.y); pk[6] = f2bf(f1.z); pk[7] = f2bf(f1.w);
        *(u16x8*)&Xlds[r * PX + c] = pk;
    }
    stage_softmax(0);
    __syncthreads();
    xf_read();

    // ================= layer loop =================
    #pragma unroll 1
    for (int l = 0; l < LNUM; ++l) {
        const int sbase = l * ENUM;

        // ===== G1+G2 for this wave's two experts (barrier-free) =====
        #pragma unroll
        for (int pe = 0; pe < 2; ++pe) {
            const int e = wv + pe * 4;
            const int s = sbase + e;

            // ---- G1: h1 = relu(x @ W1^T + b1), 4 feat-tiles of 16 ----
            // lane -> feats ft*16+q*4+rr, rows mt*16+n15 (transposed MFMA)
            #pragma unroll
            for (int ft = 0; ft < 4; ++ft) {
                u16x8 w1f[8];
                const unsigned short* p1 =
                    Wf + WS1_OFF + (size_t)s * 16384 + ft * 4096 + lane * 8;
                #pragma unroll
                for (int kt = 0; kt < 8; ++kt)
                    w1f[kt] = *(const u16x8*)(p1 + kt * 512);
                f32x4 a1[2] = {Z4, Z4};
                #pragma unroll
                for (int kt = 0; kt < 8; ++kt) {
                    a1[0] = mfma16(w1f[kt], xf[0][kt], a1[0]);
                    a1[1] = mfma16(w1f[kt], xf[1][kt], a1[1]);
                }
                const float4 bb1 = *(const float4*)(b1 + s * 64 + ft * 16 + q * 4);
                #pragma unroll
                for (int mt = 0; mt < 2; ++mt) {
                    u16x4 pk;
                    #pragma unroll
                    for (int rr = 0; rr < 4; ++rr)
                        pk[rr] = f2bf(fmaxf(a1[mt][rr] + bb1[rr], 0.f));
                    *(u16x4*)&H1W[wv][(mt*16 + n15) * PH1 + ft*16 + q*4] = pk;
                }
            }

            // ---- G2: h2 = relu(h1 @ W2^T + b2) * sw[e] ----
            // intra-wave H1W write->read: compiler-ordered lgkmcnt, no barrier
            {
                u16x8 w2f[2][2];
                const unsigned short* p2 =
                    Wf + WS2_OFF + (size_t)s * 2048 + lane * 8;
                #pragma unroll
                for (int f2 = 0; f2 < 2; ++f2)
                    #pragma unroll
                    for (int kt = 0; kt < 2; ++kt)
                        w2f[f2][kt] = *(const u16x8*)(p2 + f2*1024 + kt*512);
                u16x8 h1f[2][2];
                #pragma unroll
                for (int mt = 0; mt < 2; ++mt)
                    #pragma unroll
                    for (int kt = 0; kt < 2; ++kt)
                        h1f[mt][kt] = *(const u16x8*)
                            &H1W[wv][(mt*16 + n15) * PH1 + q*8 + kt*32];
                f32x4 a2[2][2] = {{Z4, Z4}, {Z4, Z4}};
                #pragma unroll
                for (int f2 = 0; f2 < 2; ++f2)
                    #pragma unroll
                    for (int mt = 0; mt < 2; ++mt)
                        #pragma unroll
                        for (int kt = 0; kt < 2; ++kt)
                            a2[f2][mt] = mfma16(w2f[f2][kt], h1f[mt][kt], a2[f2][mt]);
                float swv[2];
                #pragma unroll
                for (int mt = 0; mt < 2; ++mt)
                    swv[mt] = SWlds[(mt*16 + n15) * PSW + e];
                #pragma unroll
                for (int f2 = 0; f2 < 2; ++f2) {
                    const float4 bb2 = *(const float4*)(b2 + s * 32 + f2 * 16 + q * 4);
                    #pragma unroll
                    for (int mt = 0; mt < 2; ++mt) {
                        u16x4 pk;
                        #pragma unroll
                        for (int rr = 0; rr < 4; ++rr)
                            pk[rr] = f2bf(fmaxf(a2[f2][mt][rr] + bb2[rr], 0.f) * swv[mt]);
                        *(u16x4*)&H2T[e][(mt*16 + n15) * PH2 + f2*16 + q*4] = pk;
                    }
                }
            }
        }

        lbar();                     // all 8 experts' h2 ready (only barrier mid-layer)

        // ===== ACC init (deferred here so ACC is dead during G1/G2) =====
        acc_init(l);

        // ===== G3: all 8 experts, this wave's col group wv =====
        #pragma unroll
        for (int e = 0; e < ENUM; ++e) {
            const int s = sbase + e;
            u16x8 w3f[4];
            const unsigned short* p3 = w3base + (size_t)s * 8192;
            #pragma unroll
            for (int nt = 0; nt < 4; ++nt)
                w3f[nt] = *(const u16x8*)(p3 + nt * 512);
            u16x8 h0 = *(const u16x8*)&H2T[e][(n15) * PH2 + q*8];
            u16x8 h1v = *(const u16x8*)&H2T[e][(16 + n15) * PH2 + q*8];
            #pragma unroll
            for (int nt = 0; nt < 4; ++nt) {
                ACC[0][nt] = mfma16(h0,  w3f[nt], ACC[0][nt]);
                ACC[1][nt] = mfma16(h1v, w3f[nt], ACC[1][nt]);
            }
        }

        // ===== layer transition =====
        if (l < LNUM - 1) {
            x_write();
            lbar();
            xf_read();
            stage_softmax(l + 1);
            lbar();
        }
    }

    // ================= final store (fp32) =================
    #pragma unroll
    for (int mt = 0; mt < 2; ++mt)
        #pragma unroll
        for (int nt = 0; nt < 4; ++nt)
            #pragma unroll
            for (int rr = 0; rr < 4; ++rr)
                out[(size_t)(b0 + mt*16 + q*4 + rr) * DDIM
                    + wv*64 + nt*16 + n15] = ACC[mt][nt][rr];
}

extern "C" void kernel_launch(void* const* d_in, const int* in_sizes, int n_in,
                              void* d_out, int out_size, void* d_ws, size_t ws_size,
                              hipStream_t stream) {
    const float* src   = (const float*)d_in[0];
    const float* W1    = (const float*)d_in[1];
    const float* b1    = (const float*)d_in[2];
    const float* W2    = (const float*)d_in[3];
    const float* b2    = (const float*)d_in[4];
    const float* W3    = (const float*)d_in[5];
    const float* b3    = (const float*)d_in[6];
    const float* masks = (const float*)d_in[7];
    float* out = (float*)d_out;
    unsigned short* ws = (unsigned short*)d_ws;   // needs 3,407,872 B

    hipLaunchKernelGGL(cvt_w_frag, dim3(832), dim3(256), 0, stream, W1, W2, W3, ws);
    hipLaunchKernelGGL(moe_fused, dim3(BSZ / BT), dim3(NTHR), 0, stream,
                       src, ws, b1, b2, b3, masks, out);
}